// Round 6
// baseline (701.989 us; speedup 1.0000x reference)
//
#include <hip/hip_runtime.h>
#include <stdint.h>

#define S_DIM 2
#define B_DIM 2048
#define D_DIM 1024
#define H_DIM 2048
#define E_DIM 8
#define O_DIM 1024
#define NTOK 4096            // S*B
#define CAP 12288            // pair capacity (normal total = 8192)

typedef __attribute__((ext_vector_type(8))) short bf16x8;
typedef __attribute__((ext_vector_type(4))) float f32x4;

__device__ __forceinline__ unsigned short f2bf(float f) {
    union { float f; uint32_t i; } c; c.f = f;
    uint32_t r = c.i + 0x7FFFu + ((c.i >> 16) & 1u);
    return (unsigned short)(r >> 16);
}
__device__ __forceinline__ float bf2f(unsigned short u) {
    union { uint32_t i; float f; } c; c.i = (uint32_t)u << 16;
    return c.f;
}
__device__ __forceinline__ uint32_t pack2(float a, float b) {
    return (uint32_t)f2bf(a) | ((uint32_t)f2bf(b) << 16);
}
// read 8 fp32, round to bf16, write 16B
__device__ __forceinline__ void stage8(const float* __restrict__ src,
                                       unsigned short* __restrict__ dst) {
    float4 f0 = *(const float4*)src;
    float4 f1 = *(const float4*)(src + 4);
    int4 v;
    v.x = (int)pack2(f0.x, f0.y);
    v.y = (int)pack2(f0.z, f0.w);
    v.z = (int)pack2(f1.x, f1.y);
    v.w = (int)pack2(f1.z, f1.w);
    *(int4*)dst = v;
}

// async global(16B)->LDS. Global addr is per-lane; LDS dest must be wave-uniform
// (HW adds lane*16).
__device__ __forceinline__ void glds16(const unsigned short* g, unsigned short* l) {
    __builtin_amdgcn_global_load_lds(
        (__attribute__((address_space(1))) void*)g,
        (__attribute__((address_space(3))) void*)l,
        16, 0, 0);
}

// ---------------------------------------------------------------------------
// Kernel 0: fp32 -> bf16 bulk convert. 8 elems / thread.
// ---------------------------------------------------------------------------
__global__ __launch_bounds__(256) void convert_kernel(
    const float* __restrict__ src, unsigned short* __restrict__ dst, int n8)
{
    int i = blockIdx.x * blockDim.x + threadIdx.x;
    if (i < n8) stage8(src + (size_t)i * 8, dst + (size_t)i * 8);
}

// ---------------------------------------------------------------------------
// Kernel 1: gating (pure fp32 — must reproduce reference top-2 selection).
// ---------------------------------------------------------------------------
__global__ __launch_bounds__(256) void gating_kernel(
    const float* __restrict__ xs,
    const float* __restrict__ Wg,
    const float* __restrict__ bvec,
    float* __restrict__ probs_out,
    int* __restrict__ counts,
    int* __restrict__ sel_cnt,
    int* __restrict__ sel_e,
    float* __restrict__ sel_g,
    unsigned short* __restrict__ xs_bf)
{
    const int wave = threadIdx.x >> 6;
    const int lane = threadIdx.x & 63;
    const int t = blockIdx.x * 4 + wave;
    const float* x = xs + (size_t)t * D_DIM;

    float acc[8];
#pragma unroll
    for (int e = 0; e < 8; ++e) acc[e] = 0.f;

#pragma unroll
    for (int i = 0; i < D_DIM / 64; ++i) {
        int d = i * 64 + lane;
        float xv = x[d];
        xs_bf[(size_t)t * D_DIM + d] = f2bf(xv);
        float4 w0 = *(const float4*)(Wg + (size_t)d * 8);
        float4 w1 = *(const float4*)(Wg + (size_t)d * 8 + 4);
        acc[0] += xv * w0.x; acc[1] += xv * w0.y;
        acc[2] += xv * w0.z; acc[3] += xv * w0.w;
        acc[4] += xv * w1.x; acc[5] += xv * w1.y;
        acc[6] += xv * w1.z; acc[7] += xv * w1.w;
    }
#pragma unroll
    for (int off = 32; off > 0; off >>= 1) {
#pragma unroll
        for (int e = 0; e < 8; ++e)
            acc[e] += __shfl_down(acc[e], off);
    }

    if (lane == 0) {
        float Hg[8];
#pragma unroll
        for (int e = 0; e < 8; ++e) Hg[e] = acc[e] + bvec[e];

        int a1 = 0;
#pragma unroll
        for (int e = 1; e < 8; ++e) if (Hg[e] > Hg[a1]) a1 = e;
        float m1 = Hg[a1];
        float m2 = -1e30f;
#pragma unroll
        for (int e = 0; e < 8; ++e) if (e != a1 && Hg[e] > m2) m2 = Hg[e];

        float ex[8]; float sum = 0.f;
#pragma unroll
        for (int e = 0; e < 8; ++e) { ex[e] = expf(Hg[e] - m1); sum += ex[e]; }
        float inv = 1.f / sum;
#pragma unroll
        for (int e = 0; e < 8; ++e)
            probs_out[(size_t)t * 8 + e] = ex[e] * inv;

        float den = 0.f;
#pragma unroll
        for (int e = 0; e < 8; ++e) if (Hg[e] >= m2) den += ex[e];
        float invd = 1.f / den;
        int n = 0;
#pragma unroll
        for (int e = 0; e < 8; ++e) {
            if (Hg[e] >= m2) {
                sel_e[t * 8 + n] = e;
                sel_g[t * 8 + n] = ex[e] * invd;
                ++n;
                atomicAdd(&counts[e], 1);
            }
        }
        sel_cnt[t] = n;
    }
}

// ---------------------------------------------------------------------------
// Kernel 2: exclusive scan of 8 expert counts.
// ---------------------------------------------------------------------------
__global__ void scan_kernel(const int* __restrict__ counts, int* __restrict__ offsets)
{
    if (threadIdx.x == 0) {
        int tot = 0;
#pragma unroll
        for (int e = 0; e < 8; ++e) { offsets[e] = tot; tot += counts[e]; }
    }
}

// ---------------------------------------------------------------------------
// Kernel 3: scatter tokens into per-expert compacted pair lists.
// ---------------------------------------------------------------------------
__global__ __launch_bounds__(256) void scatter_kernel(
    const int* __restrict__ sel_cnt,
    const int* __restrict__ sel_e,
    const float* __restrict__ sel_g,
    const int* __restrict__ offsets,
    int* __restrict__ cursors,
    int* __restrict__ pair_token,
    float* __restrict__ pair_gate,
    int* __restrict__ tok_slot)
{
    int t = blockIdx.x * blockDim.x + threadIdx.x;
    if (t >= NTOK) return;
    int n = sel_cnt[t];
    for (int i = 0; i < n && i < 8; ++i) {
        int e = sel_e[t * 8 + i];
        int r = atomicAdd(&cursors[e], 1);
        int slot = offsets[e] + r;
        if (slot < CAP) {
            pair_token[slot] = t;
            pair_gate[slot]  = sel_g[t * 8 + i];
            tok_slot[t * 8 + i] = slot;
        } else {
            tok_slot[t * 8 + i] = -1;
        }
    }
}

// ===========================================================================
// 256x256 8-phase grouped GEMM machinery (T2+T3+T4+T5, guide §5 template).
// 512 threads = 8 waves (2M x 4N). BK=64. LDS 128KB double-buffered.
// Per K-tile: 4 phases {12 ds_read || 16 MFMA}; all 8 global_load_lds for the
// NEXT tile issued at phase 0, drained by ONE vmcnt(0) at phase 3 (~4 phases
// of overlap). Raw s_barrier (no vmcnt drain) between phases.
// ===========================================================================
#define MFMA_PHASE(BUF, MG, NG, DOSTAGE, K0N, DODRAIN)                          \
    {                                                                           \
        bf16x8 af[4][2], bfr[2][2];                                             \
        _Pragma("unroll")                                                       \
        for (int x = 0; x < 4; ++x)                                             \
            _Pragma("unroll")                                                   \
            for (int ks = 0; ks < 2; ++ks)                                      \
                af[x][ks] = *(const bf16x8*)&As[BUF][aBase + ((MG)*4 + x) * 1024 \
                                                 + ((ks * 4 + kq) ^ swz) * 8];  \
        _Pragma("unroll")                                                       \
        for (int y = 0; y < 2; ++y)                                             \
            _Pragma("unroll")                                                   \
            for (int ks = 0; ks < 2; ++ks)                                      \
                bfr[y][ks] = *(const bf16x8*)&Bs[BUF][bBase + ((NG)*2 + y) * 1024\
                                                  + ((ks * 4 + kq) ^ swz) * 8]; \
        if (DOSTAGE) {                                                          \
            _Pragma("unroll")                                                   \
            for (int i = 0; i < 4; ++i) {                                       \
                glds16(aSrc[i] + (K0N), &As[(BUF) ^ 1][dstOff[i]]);             \
                glds16(bSrc[i] + (K0N), &Bs[(BUF) ^ 1][dstOff[i]]);             \
            }                                                                   \
        }                                                                       \
        __builtin_amdgcn_s_barrier();                                           \
        __builtin_amdgcn_s_setprio(1);                                          \
        _Pragma("unroll")                                                       \
        for (int x = 0; x < 4; ++x)                                             \
            _Pragma("unroll")                                                   \
            for (int y = 0; y < 2; ++y)                                         \
                _Pragma("unroll")                                               \
                for (int ks = 0; ks < 2; ++ks)                                  \
                    acc[(MG)*4 + x][(NG)*2 + y] =                               \
                        __builtin_amdgcn_mfma_f32_16x16x32_bf16(                \
                            af[x][ks], bfr[y][ks], acc[(MG)*4 + x][(NG)*2 + y], \
                            0, 0, 0);                                           \
        __builtin_amdgcn_s_setprio(0);                                          \
        if (DODRAIN) asm volatile("s_waitcnt vmcnt(0)" ::: "memory");           \
        __builtin_amdgcn_s_barrier();                                           \
    }

#define KTILE(BUF, DOSTAGE, K0N)                    \
    MFMA_PHASE(BUF, 0, 0, DOSTAGE, K0N, false)      \
    MFMA_PHASE(BUF, 0, 1, false,   0,   false)      \
    MFMA_PHASE(BUF, 1, 0, false,   0,   false)      \
    MFMA_PHASE(BUF, 1, 1, false,   0,   DOSTAGE)

// ---------------------------------------------------------------------------
// Kernel 4: fc1 grouped GEMM, 256x256 8-phase.
// h[slot] = relu(x_bf[tok] @ fc1_wb[e]^T + fc1_b[e])  (bf16 out)
// ---------------------------------------------------------------------------
__global__ __launch_bounds__(512, 2) void fc1_kernel(
    const unsigned short* __restrict__ xs_bf,
    const unsigned short* __restrict__ fc1_wb,
    const float* __restrict__ fc1_b,
    const int* __restrict__ counts,
    const int* __restrict__ offsets,
    const int* __restrict__ pair_token,
    unsigned short* __restrict__ h)
{
    const int wg = blockIdx.x;
    const int e = wg & 7;               // XCD pin
    const int idx = wg >> 3;
    const int mtile = idx >> 3;         // 0..15
    const int ntile = idx & 7;          // 0..7
    const int cnt = counts[e];
    if (mtile * 256 >= cnt) return;
    const int offs = offsets[e];

    __shared__ __align__(16) unsigned short As[2][256 * 64];
    __shared__ __align__(16) unsigned short Bs[2][256 * 64];

    const int tid  = threadIdx.x;
    const int lane = tid & 63;
    const int wid  = tid >> 6;
    const int wr   = wid >> 2;          // 0..1
    const int wcn  = wid & 3;           // 0..3
    const int lrow = lane & 15;
    const int kq   = lane >> 4;
    const int swz  = lrow & 7;
    const int aBase = (wr * 128 + lrow) * 64;
    const int bBase = (wcn * 64 + lrow) * 64;

    const unsigned short* aSrc[4];
    const unsigned short* bSrc[4];
    int dstOff[4];
#pragma unroll
    for (int i = 0; i < 4; ++i) {
        int c = i * 512 + tid;          // 0..2047
        int row = c >> 3;               // 0..255
        int gran = (c & 7) ^ (row & 7); // G21 pre-swizzled source
        int m = mtile * 256 + row;
        int mc = m < cnt ? m : cnt - 1;
        int tok = pair_token[offs + mc];
        aSrc[i] = xs_bf + (size_t)tok * D_DIM + gran * 8;
        int n = ntile * 256 + row;
        bSrc[i] = fc1_wb + ((size_t)e * H_DIM + n) * D_DIM + gran * 8;
        dstOff[i] = (i * 512 + wid * 64) * 8;   // wave-uniform, linear
    }

    f32x4 acc[8][4];
#pragma unroll
    for (int i = 0; i < 8; ++i)
#pragma unroll
        for (int j = 0; j < 4; ++j)
            acc[i][j] = (f32x4){0.f, 0.f, 0.f, 0.f};

    // prologue: stage K-tile 0 into buf 0
#pragma unroll
    for (int i = 0; i < 4; ++i) {
        glds16(aSrc[i], &As[0][dstOff[i]]);
        glds16(bSrc[i], &Bs[0][dstOff[i]]);
    }
    asm volatile("s_waitcnt vmcnt(0)" ::: "memory");
    __builtin_amdgcn_s_barrier();

    const int NT = D_DIM / 64;          // 16 (even)
    for (int t = 0; t < NT; t += 2) {
        const int k1 = (t + 1) * 64;
        const int k2 = (t + 2) * 64;
        const bool s2 = (t + 2) < NT;
        KTILE(0, true, k1)
        KTILE(1, s2, k2)
    }

    int ncol[4]; float bias[4];
#pragma unroll
    for (int j = 0; j < 4; ++j) {
        ncol[j] = ntile * 256 + wcn * 64 + j * 16 + lrow;
        bias[j] = fc1_b[e * H_DIM + ncol[j]];
    }
#pragma unroll
    for (int i = 0; i < 8; ++i) {
#pragma unroll
        for (int r = 0; r < 4; ++r) {
            int m = mtile * 256 + wr * 128 + i * 16 + kq * 4 + r;
            if (m < cnt) {
                size_t base = (size_t)(offs + m) * H_DIM;
#pragma unroll
                for (int j = 0; j < 4; ++j) {
                    float v = acc[i][j][r] + bias[j];
                    h[base + ncol[j]] = f2bf(v > 0.f ? v : 0.f);
                }
            }
        }
    }
}

// ---------------------------------------------------------------------------
// Kernel 5: fc2 grouped GEMM, 256x256 8-phase. Plain bf16 stores of pre-gated
// expert output eo_bf[slot] = (acc+bias)*g/S.
// ---------------------------------------------------------------------------
__global__ __launch_bounds__(512, 2) void fc2_kernel(
    const unsigned short* __restrict__ h,
    const unsigned short* __restrict__ fc2_wb,
    const float* __restrict__ fc2_b,
    const int* __restrict__ counts,
    const int* __restrict__ offsets,
    const float* __restrict__ pair_gate,
    unsigned short* __restrict__ eo_bf)
{
    const int wg = blockIdx.x;
    const int e = wg & 7;               // XCD pin
    const int idx = wg >> 3;
    const int mtile = idx >> 3;
    const int ntile = idx & 7;
    const int cnt = counts[e];
    if (mtile * 256 >= cnt) return;
    const int offs = offsets[e];

    __shared__ __align__(16) unsigned short As[2][256 * 64];
    __shared__ __align__(16) unsigned short Bs[2][256 * 64];

    const int tid  = threadIdx.x;
    const int lane = tid & 63;
    const int wid  = tid >> 6;
    const int wr   = wid >> 2;
    const int wcn  = wid & 3;
    const int lrow = lane & 15;
    const int kq   = lane >> 4;
    const int swz  = lrow & 7;
    const int aBase = (wr * 128 + lrow) * 64;
    const int bBase = (wcn * 64 + lrow) * 64;

    const unsigned short* aSrc[4];
    const unsigned short* bSrc[4];
    int dstOff[4];
#pragma unroll
    for (int i = 0; i < 4; ++i) {
        int c = i * 512 + tid;
        int row = c >> 3;
        int gran = (c & 7) ^ (row & 7);
        int m = mtile * 256 + row;
        int mc = m < cnt ? m : cnt - 1;
        aSrc[i] = h + (size_t)(offs + mc) * H_DIM + gran * 8;
        int n = ntile * 256 + row;
        bSrc[i] = fc2_wb + ((size_t)e * H_DIM + n) * H_DIM + gran * 8;
        dstOff[i] = (i * 512 + wid * 64) * 8;
    }

    f32x4 acc[8][4];
#pragma unroll
    for (int i = 0; i < 8; ++i)
#pragma unroll
        for (int j = 0; j < 4; ++j)
            acc[i][j] = (f32x4){0.f, 0.f, 0.f, 0.f};

#pragma unroll
    for (int i = 0; i < 4; ++i) {
        glds16(aSrc[i], &As[0][dstOff[i]]);
        glds16(bSrc[i], &Bs[0][dstOff[i]]);
    }
    asm volatile("s_waitcnt vmcnt(0)" ::: "memory");
    __builtin_amdgcn_s_barrier();

    const int NT = H_DIM / 64;          // 32 (even)
    for (int t = 0; t < NT; t += 2) {
        const int k1 = (t + 1) * 64;
        const int k2 = (t + 2) * 64;
        const bool s2 = (t + 2) < NT;
        KTILE(0, true, k1)
        KTILE(1, s2, k2)
    }

    int ncol[4]; float bias[4];
#pragma unroll
    for (int j = 0; j < 4; ++j) {
        ncol[j] = ntile * 256 + wcn * 64 + j * 16 + lrow;
        bias[j] = fc2_b[e * H_DIM + ncol[j]];
    }
#pragma unroll
    for (int i = 0; i < 8; ++i) {
#pragma unroll
        for (int r = 0; r < 4; ++r) {
            int m = mtile * 256 + wr * 128 + i * 16 + kq * 4 + r;
            if (m < cnt) {
                int slot = offs + m;
                float g  = pair_gate[slot] * 0.5f;   // 1/S
                size_t base = (size_t)slot * H_DIM;
#pragma unroll
                for (int j = 0; j < 4; ++j) {
                    float v = (acc[i][j][r] + bias[j]) * g;
                    eo_bf[base + ncol[j]] = f2bf(v);
                }
            }
        }
    }
}

// ---------------------------------------------------------------------------
// Kernel 5b: gather-reduce. combined_bf[b][h] = sum over s,i of eo_bf[slot][h]
// ---------------------------------------------------------------------------
__global__ __launch_bounds__(256) void reduce_kernel(
    const int* __restrict__ sel_cnt,
    const int* __restrict__ tok_slot,
    const unsigned short* __restrict__ eo_bf,
    unsigned short* __restrict__ combined_bf)
{
    const int b = blockIdx.x;
    const int h0 = threadIdx.x * 8;

    float acc[8];
#pragma unroll
    for (int j = 0; j < 8; ++j) acc[j] = 0.f;

#pragma unroll
    for (int s = 0; s < S_DIM; ++s) {
        int t = s * B_DIM + b;
        int n = sel_cnt[t];
        for (int i = 0; i < n && i < 8; ++i) {
            int slot = tok_slot[t * 8 + i];
            if (slot < 0) continue;
            bf16x8 v = *(const bf16x8*)&eo_bf[(size_t)slot * H_DIM + h0];
#pragma unroll
            for (int j = 0; j < 8; ++j)
                acc[j] += bf2f((unsigned short)v[j]);
        }
    }

    int4 o;
    o.x = (int)pack2(acc[0], acc[1]);
    o.y = (int)pack2(acc[2], acc[3]);
    o.z = (int)pack2(acc[4], acc[5]);
    o.w = (int)pack2(acc[6], acc[7]);
    *(int4*)&combined_bf[(size_t)b * H_DIM + h0] = o;
}

// ---------------------------------------------------------------------------
// Kernel 6: final GEMM, all-bf16, single-buffer 128x128 (unchanged).
// out = combined_bf @ final_wb^T + final_b (fp32 out)
// ---------------------------------------------------------------------------
__global__ __launch_bounds__(256) void final_kernel(
    const unsigned short* __restrict__ combined_bf,
    const unsigned short* __restrict__ final_wb,
    const float* __restrict__ final_b,
    float* __restrict__ out)
{
    const int mtile = blockIdx.y;
    const int ntile = blockIdx.x;

    __shared__ __align__(16) unsigned short As[128 * 64];
    __shared__ __align__(16) unsigned short Bs[128 * 64];

    const int tid  = threadIdx.x;
    const int lane = tid & 63;
    const int wave = tid >> 6;
    const int wr = wave >> 1, wc = wave & 1;
    const int lrow = lane & 15;
    const int kq   = lane >> 4;

    const unsigned short* aSrc[4];
    const unsigned short* bSrc[4];
    int dstOff[4];
#pragma unroll
    for (int i = 0; i < 4; ++i) {
        int c = i * 256 + tid;
        int row = c >> 3;
        int gran = (c & 7) ^ (row & 7);
        int m = mtile * 128 + row;
        aSrc[i] = combined_bf + (size_t)m * H_DIM + gran * 8;
        int n = ntile * 128 + row;
        bSrc[i] = final_wb + (size_t)n * H_DIM + gran * 8;
        dstOff[i] = (i * 256 + wave * 64) * 8;
    }

    f32x4 acc[4][4];
#pragma unroll
    for (int i = 0; i < 4; ++i)
#pragma unroll
        for (int j = 0; j < 4; ++j)
            acc[i][j] = (f32x4){0.f, 0.f, 0.f, 0.f};

    for (int k0 = 0; k0 < H_DIM; k0 += 64) {
        __syncthreads();
#pragma unroll
        for (int i = 0; i < 4; ++i) {
            glds16(aSrc[i] + k0, &As[dstOff[i]]);
            glds16(bSrc[i] + k0, &Bs[dstOff[i]]);
        }
        __syncthreads();
#pragma unroll
        for (int ks = 0; ks < 2; ++ks) {
            bf16x8 af[4], bfr[4];
            const int gr = ks * 4 + kq;
            const int sg = (gr ^ (lrow & 7)) * 8;
#pragma unroll
            for (int i = 0; i < 4; ++i) {
                af[i]  = *(const bf16x8*)&As[(wr * 64 + i * 16 + lrow) * 64 + sg];
                bfr[i] = *(const bf16x8*)&Bs[(wc * 64 + i * 16 + lrow) * 64 + sg];
            }
#pragma unroll
            for (int i = 0; i < 4; ++i)
#pragma unroll
                for (int j = 0; j < 4; ++j)
                    acc[i][j] = __builtin_amdgcn_mfma_f32_16x16x32_bf16(af[i], bfr[j], acc[i][j], 0, 0, 0);
        }
    }

    int ncol[4]; float bias[4];
#pragma unroll
    for (int j = 0; j < 4; ++j) {
        ncol[j] = ntile * 128 + wc * 64 + j * 16 + lrow;
        bias[j] = final_b[ncol[j]];
    }
#pragma unroll
    for (int i = 0; i < 4; ++i) {
#pragma unroll
        for (int r = 0; r < 4; ++r) {
            int m = mtile * 128 + wr * 64 + i * 16 + kq * 4 + r;
#pragma unroll
            for (int j = 0; j < 4; ++j)
                out[(size_t)m * O_DIM + ncol[j]] = acc[i][j][r] + bias[j];
        }
    }
}

// ---------------------------------------------------------------------------
extern "C" void kernel_launch(void* const* d_in, const int* in_sizes, int n_in,
                              void* d_out, int out_size, void* d_ws, size_t ws_size,
                              hipStream_t stream) {
    const float* xs      = (const float*)d_in[0];
    const float* Wg      = (const float*)d_in[1];
    const float* bvec    = (const float*)d_in[2];
    const float* fc1_w   = (const float*)d_in[3];
    const float* fc1_b   = (const float*)d_in[4];
    const float* fc2_w   = (const float*)d_in[5];
    const float* fc2_b   = (const float*)d_in[6];
    const float* final_w = (const float*)d_in[7];
    const float* final_b = (const float*)d_in[8];

    float* out = (float*)d_out;
    float* probs_out = out + (size_t)B_DIM * O_DIM;

    uint8_t* w = (uint8_t*)d_ws;
    int*   counts     = (int*)(w + 0);
    int*   cursors    = (int*)(w + 64);
    int*   offsets    = (int*)(w + 128);
    int*   sel_cnt    = (int*)(w + 256);        // 16 KB
    int*   sel_e      = (int*)(w + 0x5000);     // 128 KB
    float* sel_g      = (float*)(w + 0x25000);  // 128 KB
    int*   pair_token = (int*)(w + 0x45000);    // 48 KB
    float* pair_gate  = (float*)(w + 0x51000);  // 48 KB
    int*   tok_slot   = (int*)(w + 0x5D000);    // 128 KB -> 0x7D000
    unsigned short* h = (unsigned short*)(w + 0x1060000);       // 48 MB -> 0x4060000
    unsigned short* xs_bf   = (unsigned short*)(w + 0x4060000); // 8 MB  -> 0x4860000
    unsigned short* fc1_wb  = (unsigned short*)(w + 0x4860000); // 32 MB -> 0x6860000
    unsigned short* fc2_wb  = (unsigned short*)(w + 0x6860000); // 64 MB -> 0xA860000
    unsigned short* final_wb    = (unsigned short*)(w + 0xA860000); // 4 MB -> 0xAC60000
    unsigned short* combined_bf = (unsigned short*)(w + 0xAC60000); // 8 MB -> 0xB460000
    unsigned short* eo_bf       = (unsigned short*)(w + 0xB460000); // 48 MB -> 0xE460000

    hipMemsetAsync(w, 0, 256, stream);

    // weight fp32 -> bf16 (once per launch)
    convert_kernel<<<(E_DIM * H_DIM * D_DIM / 8) / 256, 256, 0, stream>>>(
        fc1_w, fc1_wb, E_DIM * H_DIM * D_DIM / 8);
    convert_kernel<<<(E_DIM * H_DIM * H_DIM / 8) / 256, 256, 0, stream>>>(
        fc2_w, fc2_wb, E_DIM * H_DIM * H_DIM / 8);
    convert_kernel<<<(O_DIM * H_DIM / 8) / 256, 256, 0, stream>>>(
        final_w, final_wb, O_DIM * H_DIM / 8);

    gating_kernel<<<NTOK / 4, 256, 0, stream>>>(xs, Wg, bvec, probs_out,
                                                counts, sel_cnt, sel_e, sel_g, xs_bf);
    scan_kernel<<<1, 64, 0, stream>>>(counts, offsets);
    scatter_kernel<<<NTOK / 256, 256, 0, stream>>>(sel_cnt, sel_e, sel_g, offsets,
                                                   cursors, pair_token, pair_gate,
                                                   tok_slot);
    // 1D grids: expert = wgid&7 (XCD pin); 16 mtiles x 8 ntiles per expert.
    fc1_kernel<<<E_DIM * (NTOK / 256) * (H_DIM / 256), 512, 0, stream>>>(
        xs_bf, fc1_wb, fc1_b, counts, offsets, pair_token, h);
    fc2_kernel<<<E_DIM * (NTOK / 256) * (H_DIM / 256), 512, 0, stream>>>(
        h, fc2_wb, fc2_b, counts, offsets, pair_gate, eo_bf);
    reduce_kernel<<<B_DIM, 256, 0, stream>>>(sel_cnt, tok_slot, eo_bf, combined_bf);
    final_kernel<<<dim3(O_DIM / 128, B_DIM / 128), 256, 0, stream>>>(
        combined_bf, final_wb, final_b, out);
}

// Round 8
// 638.360 us; speedup vs baseline: 1.0997x; 1.0997x over previous
//
#include <hip/hip_runtime.h>
#include <stdint.h>

#define S_DIM 2
#define B_DIM 2048
#define D_DIM 1024
#define H_DIM 2048
#define E_DIM 8
#define O_DIM 1024
#define NTOK 4096            // S*B
#define CAP 12288            // pair capacity (normal total = 8192)

typedef __attribute__((ext_vector_type(8))) short bf16x8;
typedef __attribute__((ext_vector_type(4))) float f32x4;

__device__ __forceinline__ unsigned short f2bf(float f) {
    union { float f; uint32_t i; } c; c.f = f;
    uint32_t r = c.i + 0x7FFFu + ((c.i >> 16) & 1u);
    return (unsigned short)(r >> 16);
}
__device__ __forceinline__ float bf2f(unsigned short u) {
    union { uint32_t i; float f; } c; c.i = (uint32_t)u << 16;
    return c.f;
}
__device__ __forceinline__ uint32_t pack2(float a, float b) {
    return (uint32_t)f2bf(a) | ((uint32_t)f2bf(b) << 16);
}
// read 8 fp32, round to bf16, write 16B
__device__ __forceinline__ void stage8(const float* __restrict__ src,
                                       unsigned short* __restrict__ dst) {
    float4 f0 = *(const float4*)src;
    float4 f1 = *(const float4*)(src + 4);
    int4 v;
    v.x = (int)pack2(f0.x, f0.y);
    v.y = (int)pack2(f0.z, f0.w);
    v.z = (int)pack2(f1.x, f1.y);
    v.w = (int)pack2(f1.z, f1.w);
    *(int4*)dst = v;
}

// async global(16B)->LDS. Global addr is per-lane; LDS dest must be wave-uniform
// (HW adds lane*16).
__device__ __forceinline__ void glds16(const unsigned short* g, unsigned short* l) {
    __builtin_amdgcn_global_load_lds(
        (__attribute__((address_space(1))) void*)g,
        (__attribute__((address_space(3))) void*)l,
        16, 0, 0);
}

// ---------------------------------------------------------------------------
// Kernel 0: fp32 -> bf16 bulk convert. 8 elems / thread.
// ---------------------------------------------------------------------------
__global__ __launch_bounds__(256) void convert_kernel(
    const float* __restrict__ src, unsigned short* __restrict__ dst, int n8)
{
    int i = blockIdx.x * blockDim.x + threadIdx.x;
    if (i < n8) stage8(src + (size_t)i * 8, dst + (size_t)i * 8);
}

// ---------------------------------------------------------------------------
// Kernel 1: gating (pure fp32 — must reproduce reference top-2 selection).
// ---------------------------------------------------------------------------
__global__ __launch_bounds__(256) void gating_kernel(
    const float* __restrict__ xs,
    const float* __restrict__ Wg,
    const float* __restrict__ bvec,
    float* __restrict__ probs_out,
    int* __restrict__ counts,
    int* __restrict__ sel_cnt,
    int* __restrict__ sel_e,
    float* __restrict__ sel_g,
    unsigned short* __restrict__ xs_bf)
{
    const int wave = threadIdx.x >> 6;
    const int lane = threadIdx.x & 63;
    const int t = blockIdx.x * 4 + wave;
    const float* x = xs + (size_t)t * D_DIM;

    float acc[8];
#pragma unroll
    for (int e = 0; e < 8; ++e) acc[e] = 0.f;

#pragma unroll
    for (int i = 0; i < D_DIM / 64; ++i) {
        int d = i * 64 + lane;
        float xv = x[d];
        xs_bf[(size_t)t * D_DIM + d] = f2bf(xv);
        float4 w0 = *(const float4*)(Wg + (size_t)d * 8);
        float4 w1 = *(const float4*)(Wg + (size_t)d * 8 + 4);
        acc[0] += xv * w0.x; acc[1] += xv * w0.y;
        acc[2] += xv * w0.z; acc[3] += xv * w0.w;
        acc[4] += xv * w1.x; acc[5] += xv * w1.y;
        acc[6] += xv * w1.z; acc[7] += xv * w1.w;
    }
#pragma unroll
    for (int off = 32; off > 0; off >>= 1) {
#pragma unroll
        for (int e = 0; e < 8; ++e)
            acc[e] += __shfl_down(acc[e], off);
    }

    if (lane == 0) {
        float Hg[8];
#pragma unroll
        for (int e = 0; e < 8; ++e) Hg[e] = acc[e] + bvec[e];

        int a1 = 0;
#pragma unroll
        for (int e = 1; e < 8; ++e) if (Hg[e] > Hg[a1]) a1 = e;
        float m1 = Hg[a1];
        float m2 = -1e30f;
#pragma unroll
        for (int e = 0; e < 8; ++e) if (e != a1 && Hg[e] > m2) m2 = Hg[e];

        float ex[8]; float sum = 0.f;
#pragma unroll
        for (int e = 0; e < 8; ++e) { ex[e] = expf(Hg[e] - m1); sum += ex[e]; }
        float inv = 1.f / sum;
#pragma unroll
        for (int e = 0; e < 8; ++e)
            probs_out[(size_t)t * 8 + e] = ex[e] * inv;

        float den = 0.f;
#pragma unroll
        for (int e = 0; e < 8; ++e) if (Hg[e] >= m2) den += ex[e];
        float invd = 1.f / den;
        int n = 0;
#pragma unroll
        for (int e = 0; e < 8; ++e) {
            if (Hg[e] >= m2) {
                sel_e[t * 8 + n] = e;
                sel_g[t * 8 + n] = ex[e] * invd;
                ++n;
                atomicAdd(&counts[e], 1);
            }
        }
        sel_cnt[t] = n;
    }
}

// ---------------------------------------------------------------------------
// Kernel 2: exclusive scan of 8 expert counts.
// ---------------------------------------------------------------------------
__global__ void scan_kernel(const int* __restrict__ counts, int* __restrict__ offsets)
{
    if (threadIdx.x == 0) {
        int tot = 0;
#pragma unroll
        for (int e = 0; e < 8; ++e) { offsets[e] = tot; tot += counts[e]; }
    }
}

// ---------------------------------------------------------------------------
// Kernel 3: scatter tokens into per-expert compacted pair lists.
// ---------------------------------------------------------------------------
__global__ __launch_bounds__(256) void scatter_kernel(
    const int* __restrict__ sel_cnt,
    const int* __restrict__ sel_e,
    const float* __restrict__ sel_g,
    const int* __restrict__ offsets,
    int* __restrict__ cursors,
    int* __restrict__ pair_token,
    float* __restrict__ pair_gate,
    int* __restrict__ tok_slot)
{
    int t = blockIdx.x * blockDim.x + threadIdx.x;
    if (t >= NTOK) return;
    int n = sel_cnt[t];
    for (int i = 0; i < n && i < 8; ++i) {
        int e = sel_e[t * 8 + i];
        int r = atomicAdd(&cursors[e], 1);
        int slot = offsets[e] + r;
        if (slot < CAP) {
            pair_token[slot] = t;
            pair_gate[slot]  = sel_g[t * 8 + i];
            tok_slot[t * 8 + i] = slot;
        } else {
            tok_slot[t * 8 + i] = -1;
        }
    }
}

// ===========================================================================
// Grouped GEMM, 128x256 tile, BK=64, 256 threads = 4 waves (1M x 4N).
// PROVEN R5 2-barrier loop (no dbuf, no 8-phase — both measured regressions).
// L2-window blocking: per expert (cnt~1024) 8 mtiles x 8 ntiles = 64 blocks
// = 2/CU on the pinned XCD; all march K together, so the live K-window
// (A 128KB + B 256KB) is L2-resident and each panel byte crosses L3 once
// (~1GB -> ~96MB L3 traffic vs R5's 128^2 blocking).
// LDS 48KB -> 2 blocks/CU; VGPR ~230 -> 2 waves/SIMD.
// ===========================================================================

// ---------------------------------------------------------------------------
// Kernel 4: fc1. h[slot] = relu(x_bf[tok] @ fc1_wb[e]^T + fc1_b[e]) (bf16 out)
// ---------------------------------------------------------------------------
__global__ __launch_bounds__(256, 2) void fc1_kernel(
    const unsigned short* __restrict__ xs_bf,
    const unsigned short* __restrict__ fc1_wb,
    const float* __restrict__ fc1_b,
    const int* __restrict__ counts,
    const int* __restrict__ offsets,
    const int* __restrict__ pair_token,
    unsigned short* __restrict__ h)
{
    const int wg = blockIdx.x;
    const int e = wg & 7;               // XCD pin
    const int idx = wg >> 3;
    const int mtile = idx >> 3;         // 0..31 (ntile fastest)
    const int ntile = idx & 7;          // 0..7
    const int cnt = counts[e];
    if (mtile * 128 >= cnt) return;
    const int offs = offsets[e];

    __shared__ __align__(16) unsigned short As[128 * 64];   // 16 KB
    __shared__ __align__(16) unsigned short Bs[256 * 64];   // 32 KB

    const int tid  = threadIdx.x;
    const int lane = tid & 63;
    const int wid  = tid >> 6;          // 0..3 = N-quadrant
    const int lrow = lane & 15;
    const int kq   = lane >> 4;
    const int swz  = lrow & 7;

    const unsigned short* aSrc[4];
    int aDst[4];
#pragma unroll
    for (int i = 0; i < 4; ++i) {
        int c = i * 256 + tid;          // 0..1023 (128 rows x 8 granules)
        int row = c >> 3;
        int gran = (c & 7) ^ (row & 7); // G21 pre-swizzled source
        int m = mtile * 128 + row;
        int mc = m < cnt ? m : cnt - 1;
        int tok = pair_token[offs + mc];
        aSrc[i] = xs_bf + (size_t)tok * D_DIM + gran * 8;
        aDst[i] = (i * 256 + wid * 64) * 8;
    }
    const unsigned short* bSrc[8];
    int bDst[8];
#pragma unroll
    for (int i = 0; i < 8; ++i) {
        int c = i * 256 + tid;          // 0..2047 (256 rows x 8 granules)
        int row = c >> 3;
        int gran = (c & 7) ^ (row & 7);
        int n = ntile * 256 + row;
        bSrc[i] = fc1_wb + ((size_t)e * H_DIM + n) * D_DIM + gran * 8;
        bDst[i] = (i * 256 + wid * 64) * 8;
    }

    f32x4 acc[8][4];
#pragma unroll
    for (int i = 0; i < 8; ++i)
#pragma unroll
        for (int j = 0; j < 4; ++j)
            acc[i][j] = (f32x4){0.f, 0.f, 0.f, 0.f};

    for (int k0 = 0; k0 < D_DIM; k0 += 64) {
        __syncthreads();
#pragma unroll
        for (int i = 0; i < 4; ++i) glds16(aSrc[i] + k0, &As[aDst[i]]);
#pragma unroll
        for (int i = 0; i < 8; ++i) glds16(bSrc[i] + k0, &Bs[bDst[i]]);
        __syncthreads();
#pragma unroll
        for (int ks = 0; ks < 2; ++ks) {
            const int sg = ((ks * 4 + kq) ^ swz) * 8;
            bf16x8 af[8], bfr[4];
#pragma unroll
            for (int i = 0; i < 8; ++i)
                af[i] = *(const bf16x8*)&As[(i * 16 + lrow) * 64 + sg];
#pragma unroll
            for (int j = 0; j < 4; ++j)
                bfr[j] = *(const bf16x8*)&Bs[(wid * 64 + j * 16 + lrow) * 64 + sg];
#pragma unroll
            for (int i = 0; i < 8; ++i)
#pragma unroll
                for (int j = 0; j < 4; ++j)
                    acc[i][j] = __builtin_amdgcn_mfma_f32_16x16x32_bf16(
                        af[i], bfr[j], acc[i][j], 0, 0, 0);
        }
    }

    int ncol[4]; float bias[4];
#pragma unroll
    for (int j = 0; j < 4; ++j) {
        ncol[j] = ntile * 256 + wid * 64 + j * 16 + lrow;
        bias[j] = fc1_b[e * H_DIM + ncol[j]];
    }
#pragma unroll
    for (int i = 0; i < 8; ++i) {
#pragma unroll
        for (int r = 0; r < 4; ++r) {
            int m = mtile * 128 + i * 16 + kq * 4 + r;
            if (m < cnt) {
                size_t base = (size_t)(offs + m) * H_DIM;
#pragma unroll
                for (int j = 0; j < 4; ++j) {
                    float v = acc[i][j][r] + bias[j];
                    h[base + ncol[j]] = f2bf(v > 0.f ? v : 0.f);
                }
            }
        }
    }
}

// ---------------------------------------------------------------------------
// Kernel 5: fc2. Plain bf16 stores of pre-gated eo_bf[slot] = (acc+bias)*g/S.
// ---------------------------------------------------------------------------
__global__ __launch_bounds__(256, 2) void fc2_kernel(
    const unsigned short* __restrict__ h,
    const unsigned short* __restrict__ fc2_wb,
    const float* __restrict__ fc2_b,
    const int* __restrict__ counts,
    const int* __restrict__ offsets,
    const float* __restrict__ pair_gate,
    unsigned short* __restrict__ eo_bf)
{
    const int wg = blockIdx.x;
    const int e = wg & 7;               // XCD pin
    const int idx = wg >> 3;
    const int mtile = idx >> 3;
    const int ntile = idx & 7;
    const int cnt = counts[e];
    if (mtile * 128 >= cnt) return;
    const int offs = offsets[e];

    __shared__ __align__(16) unsigned short As[128 * 64];
    __shared__ __align__(16) unsigned short Bs[256 * 64];

    const int tid  = threadIdx.x;
    const int lane = tid & 63;
    const int wid  = tid >> 6;
    const int lrow = lane & 15;
    const int kq   = lane >> 4;
    const int swz  = lrow & 7;

    const unsigned short* aSrc[4];
    int aDst[4];
#pragma unroll
    for (int i = 0; i < 4; ++i) {
        int c = i * 256 + tid;
        int row = c >> 3;
        int gran = (c & 7) ^ (row & 7);
        int m = mtile * 128 + row;
        int mc = m < cnt ? m : cnt - 1;
        aSrc[i] = h + (size_t)(offs + mc) * H_DIM + gran * 8;
        aDst[i] = (i * 256 + wid * 64) * 8;
    }
    const unsigned short* bSrc[8];
    int bDst[8];
#pragma unroll
    for (int i = 0; i < 8; ++i) {
        int c = i * 256 + tid;
        int row = c >> 3;
        int gran = (c & 7) ^ (row & 7);
        int n = ntile * 256 + row;
        bSrc[i] = fc2_wb + ((size_t)e * H_DIM + n) * H_DIM + gran * 8;
        bDst[i] = (i * 256 + wid * 64) * 8;
    }

    f32x4 acc[8][4];
#pragma unroll
    for (int i = 0; i < 8; ++i)
#pragma unroll
        for (int j = 0; j < 4; ++j)
            acc[i][j] = (f32x4){0.f, 0.f, 0.f, 0.f};

    for (int k0 = 0; k0 < H_DIM; k0 += 64) {
        __syncthreads();
#pragma unroll
        for (int i = 0; i < 4; ++i) glds16(aSrc[i] + k0, &As[aDst[i]]);
#pragma unroll
        for (int i = 0; i < 8; ++i) glds16(bSrc[i] + k0, &Bs[bDst[i]]);
        __syncthreads();
#pragma unroll
        for (int ks = 0; ks < 2; ++ks) {
            const int sg = ((ks * 4 + kq) ^ swz) * 8;
            bf16x8 af[8], bfr[4];
#pragma unroll
            for (int i = 0; i < 8; ++i)
                af[i] = *(const bf16x8*)&As[(i * 16 + lrow) * 64 + sg];
#pragma unroll
            for (int j = 0; j < 4; ++j)
                bfr[j] = *(const bf16x8*)&Bs[(wid * 64 + j * 16 + lrow) * 64 + sg];
#pragma unroll
            for (int i = 0; i < 8; ++i)
#pragma unroll
                for (int j = 0; j < 4; ++j)
                    acc[i][j] = __builtin_amdgcn_mfma_f32_16x16x32_bf16(
                        af[i], bfr[j], acc[i][j], 0, 0, 0);
        }
    }

    int ncol[4]; float bias[4];
#pragma unroll
    for (int j = 0; j < 4; ++j) {
        ncol[j] = ntile * 256 + wid * 64 + j * 16 + lrow;
        bias[j] = fc2_b[e * H_DIM + ncol[j]];
    }
#pragma unroll
    for (int i = 0; i < 8; ++i) {
#pragma unroll
        for (int r = 0; r < 4; ++r) {
            int m = mtile * 128 + i * 16 + kq * 4 + r;
            if (m < cnt) {
                int slot = offs + m;
                float g  = pair_gate[slot] * 0.5f;   // 1/S
                size_t base = (size_t)slot * H_DIM;
#pragma unroll
                for (int j = 0; j < 4; ++j) {
                    float v = (acc[i][j][r] + bias[j]) * g;
                    eo_bf[base + ncol[j]] = f2bf(v);
                }
            }
        }
    }
}

// ---------------------------------------------------------------------------
// Kernel 5b: gather-reduce. combined_bf[b][h] = sum over s,i of eo_bf[slot][h]
// ---------------------------------------------------------------------------
__global__ __launch_bounds__(256) void reduce_kernel(
    const int* __restrict__ sel_cnt,
    const int* __restrict__ tok_slot,
    const unsigned short* __restrict__ eo_bf,
    unsigned short* __restrict__ combined_bf)
{
    const int b = blockIdx.x;
    const int h0 = threadIdx.x * 8;

    float acc[8];
#pragma unroll
    for (int j = 0; j < 8; ++j) acc[j] = 0.f;

#pragma unroll
    for (int s = 0; s < S_DIM; ++s) {
        int t = s * B_DIM + b;
        int n = sel_cnt[t];
        for (int i = 0; i < n && i < 8; ++i) {
            int slot = tok_slot[t * 8 + i];
            if (slot < 0) continue;
            bf16x8 v = *(const bf16x8*)&eo_bf[(size_t)slot * H_DIM + h0];
#pragma unroll
            for (int j = 0; j < 8; ++j)
                acc[j] += bf2f((unsigned short)v[j]);
        }
    }

    int4 o;
    o.x = (int)pack2(acc[0], acc[1]);
    o.y = (int)pack2(acc[2], acc[3]);
    o.z = (int)pack2(acc[4], acc[5]);
    o.w = (int)pack2(acc[6], acc[7]);
    *(int4*)&combined_bf[(size_t)b * H_DIM + h0] = o;
}

// ---------------------------------------------------------------------------
// Kernel 6: final GEMM, all-bf16, single-buffer 128x128 (proven, unchanged).
// out = combined_bf @ final_wb^T + final_b (fp32 out)
// ---------------------------------------------------------------------------
__global__ __launch_bounds__(256) void final_kernel(
    const unsigned short* __restrict__ combined_bf,
    const unsigned short* __restrict__ final_wb,
    const float* __restrict__ final_b,
    float* __restrict__ out)
{
    const int mtile = blockIdx.y;
    const int ntile = blockIdx.x;

    __shared__ __align__(16) unsigned short As[128 * 64];
    __shared__ __align__(16) unsigned short Bs[128 * 64];

    const int tid  = threadIdx.x;
    const int lane = tid & 63;
    const int wave = tid >> 6;
    const int wr = wave >> 1, wc = wave & 1;
    const int lrow = lane & 15;
    const int kq   = lane >> 4;

    const unsigned short* aSrc[4];
    const unsigned short* bSrc[4];
    int dstOff[4];
#pragma unroll
    for (int i = 0; i < 4; ++i) {
        int c = i * 256 + tid;
        int row = c >> 3;
        int gran = (c & 7) ^ (row & 7);
        int m = mtile * 128 + row;
        aSrc[i] = combined_bf + (size_t)m * H_DIM + gran * 8;
        int n = ntile * 128 + row;
        bSrc[i] = final_wb + (size_t)n * H_DIM + gran * 8;
        dstOff[i] = (i * 256 + wave * 64) * 8;
    }

    f32x4 acc[4][4];
#pragma unroll
    for (int i = 0; i < 4; ++i)
#pragma unroll
        for (int j = 0; j < 4; ++j)
            acc[i][j] = (f32x4){0.f, 0.f, 0.f, 0.f};

    for (int k0 = 0; k0 < H_DIM; k0 += 64) {
        __syncthreads();
#pragma unroll
        for (int i = 0; i < 4; ++i) {
            glds16(aSrc[i] + k0, &As[dstOff[i]]);
            glds16(bSrc[i] + k0, &Bs[dstOff[i]]);
        }
        __syncthreads();
#pragma unroll
        for (int ks = 0; ks < 2; ++ks) {
            bf16x8 af[4], bfr[4];
            const int gr = ks * 4 + kq;
            const int sg = (gr ^ (lrow & 7)) * 8;
#pragma unroll
            for (int i = 0; i < 4; ++i) {
                af[i]  = *(const bf16x8*)&As[(wr * 64 + i * 16 + lrow) * 64 + sg];
                bfr[i] = *(const bf16x8*)&Bs[(wc * 64 + i * 16 + lrow) * 64 + sg];
            }
#pragma unroll
            for (int i = 0; i < 4; ++i)
#pragma unroll
                for (int j = 0; j < 4; ++j)
                    acc[i][j] = __builtin_amdgcn_mfma_f32_16x16x32_bf16(af[i], bfr[j], acc[i][j], 0, 0, 0);
        }
    }

    int ncol[4]; float bias[4];
#pragma unroll
    for (int j = 0; j < 4; ++j) {
        ncol[j] = ntile * 128 + wc * 64 + j * 16 + lrow;
        bias[j] = final_b[ncol[j]];
    }
#pragma unroll
    for (int i = 0; i < 4; ++i) {
#pragma unroll
        for (int r = 0; r < 4; ++r) {
            int m = mtile * 128 + wr * 64 + i * 16 + kq * 4 + r;
#pragma unroll
            for (int j = 0; j < 4; ++j)
                out[(size_t)m * O_DIM + ncol[j]] = acc[i][j][r] + bias[j];
        }
    }
}

// ---------------------------------------------------------------------------
extern "C" void kernel_launch(void* const* d_in, const int* in_sizes, int n_in,
                              void* d_out, int out_size, void* d_ws, size_t ws_size,
                              hipStream_t stream) {
    const float* xs      = (const float*)d_in[0];
    const float* Wg      = (const float*)d_in[1];
    const float* bvec    = (const float*)d_in[2];
    const float* fc1_w   = (const float*)d_in[3];
    const float* fc1_b   = (const float*)d_in[4];
    const float* fc2_w   = (const float*)d_in[5];
    const float* fc2_b   = (const float*)d_in[6];
    const float* final_w = (const float*)d_in[7];
    const float* final_b = (const float*)d_in[8];

    float* out = (float*)d_out;
    float* probs_out = out + (size_t)B_DIM * O_DIM;

    uint8_t* w = (uint8_t*)d_ws;
    int*   counts     = (int*)(w + 0);
    int*   cursors    = (int*)(w + 64);
    int*   offsets    = (int*)(w + 128);
    int*   sel_cnt    = (int*)(w + 256);        // 16 KB
    int*   sel_e      = (int*)(w + 0x5000);     // 128 KB
    float* sel_g      = (float*)(w + 0x25000);  // 128 KB
    int*   pair_token = (int*)(w + 0x45000);    // 48 KB
    float* pair_gate  = (float*)(w + 0x51000);  // 48 KB
    int*   tok_slot   = (int*)(w + 0x5D000);    // 128 KB -> 0x7D000
    unsigned short* h = (unsigned short*)(w + 0x1060000);       // 48 MB -> 0x4060000
    unsigned short* xs_bf   = (unsigned short*)(w + 0x4060000); // 8 MB  -> 0x4860000
    unsigned short* fc1_wb  = (unsigned short*)(w + 0x4860000); // 32 MB -> 0x6860000
    unsigned short* fc2_wb  = (unsigned short*)(w + 0x6860000); // 64 MB -> 0xA860000
    unsigned short* final_wb    = (unsigned short*)(w + 0xA860000); // 4 MB -> 0xAC60000
    unsigned short* combined_bf = (unsigned short*)(w + 0xAC60000); // 8 MB -> 0xB460000
    unsigned short* eo_bf       = (unsigned short*)(w + 0xB460000); // 48 MB -> 0xE460000

    hipMemsetAsync(w, 0, 256, stream);

    // weight fp32 -> bf16 (once per launch)
    convert_kernel<<<(E_DIM * H_DIM * D_DIM / 8) / 256, 256, 0, stream>>>(
        fc1_w, fc1_wb, E_DIM * H_DIM * D_DIM / 8);
    convert_kernel<<<(E_DIM * H_DIM * H_DIM / 8) / 256, 256, 0, stream>>>(
        fc2_w, fc2_wb, E_DIM * H_DIM * H_DIM / 8);
    convert_kernel<<<(O_DIM * H_DIM / 8) / 256, 256, 0, stream>>>(
        final_w, final_wb, O_DIM * H_DIM / 8);

    gating_kernel<<<NTOK / 4, 256, 0, stream>>>(xs, Wg, bvec, probs_out,
                                                counts, sel_cnt, sel_e, sel_g, xs_bf);
    scan_kernel<<<1, 64, 0, stream>>>(counts, offsets);
    scatter_kernel<<<NTOK / 256, 256, 0, stream>>>(sel_cnt, sel_e, sel_g, offsets,
                                                   cursors, pair_token, pair_gate,
                                                   tok_slot);
    // 1D grids: expert = wgid&7 (XCD pin); ntile fastest; mtile covers up to
    // cnt=4096 (32 x 128). Early-exit blocks vacate; survivors ~2/CU per XCD.
    fc1_kernel<<<E_DIM * (NTOK / 128) * (H_DIM / 256), 256, 0, stream>>>(
        xs_bf, fc1_wb, fc1_b, counts, offsets, pair_token, h);
    fc2_kernel<<<E_DIM * (NTOK / 128) * (H_DIM / 256), 256, 0, stream>>>(
        h, fc2_wb, fc2_b, counts, offsets, pair_gate, eo_bf);
    reduce_kernel<<<B_DIM, 256, 0, stream>>>(sel_cnt, tok_slot, eo_bf, combined_bf);
    final_kernel<<<dim3(O_DIM / 128, B_DIM / 128), 256, 0, stream>>>(
        combined_bf, final_wb, final_b, out);
}

// Round 9
// 628.827 us; speedup vs baseline: 1.1163x; 1.0152x over previous
//
#include <hip/hip_runtime.h>
#include <stdint.h>

#define S_DIM 2
#define B_DIM 2048
#define D_DIM 1024
#define H_DIM 2048
#define E_DIM 8
#define O_DIM 1024
#define NTOK 4096            // S*B
#define CAP 12288            // pair capacity (normal total = 8192)

typedef __attribute__((ext_vector_type(8))) short bf16x8;
typedef __attribute__((ext_vector_type(4))) float f32x4;

__device__ __forceinline__ unsigned short f2bf(float f) {
    union { float f; uint32_t i; } c; c.f = f;
    uint32_t r = c.i + 0x7FFFu + ((c.i >> 16) & 1u);
    return (unsigned short)(r >> 16);
}
__device__ __forceinline__ float bf2f(unsigned short u) {
    union { uint32_t i; float f; } c; c.i = (uint32_t)u << 16;
    return c.f;
}
__device__ __forceinline__ uint32_t pack2(float a, float b) {
    return (uint32_t)f2bf(a) | ((uint32_t)f2bf(b) << 16);
}
// read 8 fp32, round to bf16, write 16B
__device__ __forceinline__ void stage8(const float* __restrict__ src,
                                       unsigned short* __restrict__ dst) {
    float4 f0 = *(const float4*)src;
    float4 f1 = *(const float4*)(src + 4);
    int4 v;
    v.x = (int)pack2(f0.x, f0.y);
    v.y = (int)pack2(f0.z, f0.w);
    v.z = (int)pack2(f1.x, f1.y);
    v.w = (int)pack2(f1.z, f1.w);
    *(int4*)dst = v;
}

// async global(16B)->LDS. Global addr is per-lane; LDS dest must be wave-uniform
// (HW adds lane*16).
__device__ __forceinline__ void glds16(const unsigned short* g, unsigned short* l) {
    __builtin_amdgcn_global_load_lds(
        (__attribute__((address_space(1))) void*)g,
        (__attribute__((address_space(3))) void*)l,
        16, 0, 0);
}

// ---------------------------------------------------------------------------
// Kernel 0: fused fp32 -> bf16 convert of all three weight tensors.
// Block 0 also zeroes the 256B counter region (replaces hipMemsetAsync).
// ---------------------------------------------------------------------------
#define N8_FC1   ((size_t)E_DIM * H_DIM * D_DIM / 8)   // 2,097,152
#define N8_FC2   ((size_t)E_DIM * H_DIM * H_DIM / 8)   // 4,194,304
#define N8_FINAL ((size_t)O_DIM * H_DIM / 8)           //   262,144
#define N8_TOTAL (N8_FC1 + N8_FC2 + N8_FINAL)

__global__ __launch_bounds__(256) void convert_all_kernel(
    const float* __restrict__ fc1_w,
    const float* __restrict__ fc2_w,
    const float* __restrict__ final_w,
    unsigned short* __restrict__ fc1_wb,
    unsigned short* __restrict__ fc2_wb,
    unsigned short* __restrict__ final_wb,
    int* __restrict__ ws_zero)
{
    if (blockIdx.x == 0 && threadIdx.x < 64) ws_zero[threadIdx.x] = 0;
    size_t i = (size_t)blockIdx.x * blockDim.x + threadIdx.x;
    if (i < N8_FC1) {
        stage8(fc1_w + i * 8, fc1_wb + i * 8);
    } else if (i < N8_FC1 + N8_FC2) {
        size_t j = i - N8_FC1;
        stage8(fc2_w + j * 8, fc2_wb + j * 8);
    } else if (i < N8_TOTAL) {
        size_t j = i - N8_FC1 - N8_FC2;
        stage8(final_w + j * 8, final_wb + j * 8);
    }
}

// ---------------------------------------------------------------------------
// Kernel 1: gating (pure fp32 — must reproduce reference top-2 selection).
// One wave per token. Also emits xs in bf16 (it reads all of xs anyway).
// ---------------------------------------------------------------------------
__global__ __launch_bounds__(256) void gating_kernel(
    const float* __restrict__ xs,
    const float* __restrict__ Wg,
    const float* __restrict__ bvec,
    float* __restrict__ probs_out,
    int* __restrict__ counts,
    int* __restrict__ sel_cnt,
    int* __restrict__ sel_e,
    float* __restrict__ sel_g,
    unsigned short* __restrict__ xs_bf)
{
    const int wave = threadIdx.x >> 6;
    const int lane = threadIdx.x & 63;
    const int t = blockIdx.x * 4 + wave;
    const float* x = xs + (size_t)t * D_DIM;

    float acc[8];
#pragma unroll
    for (int e = 0; e < 8; ++e) acc[e] = 0.f;

#pragma unroll
    for (int i = 0; i < D_DIM / 64; ++i) {
        int d = i * 64 + lane;
        float xv = x[d];
        xs_bf[(size_t)t * D_DIM + d] = f2bf(xv);
        float4 w0 = *(const float4*)(Wg + (size_t)d * 8);
        float4 w1 = *(const float4*)(Wg + (size_t)d * 8 + 4);
        acc[0] += xv * w0.x; acc[1] += xv * w0.y;
        acc[2] += xv * w0.z; acc[3] += xv * w0.w;
        acc[4] += xv * w1.x; acc[5] += xv * w1.y;
        acc[6] += xv * w1.z; acc[7] += xv * w1.w;
    }
#pragma unroll
    for (int off = 32; off > 0; off >>= 1) {
#pragma unroll
        for (int e = 0; e < 8; ++e)
            acc[e] += __shfl_down(acc[e], off);
    }

    if (lane == 0) {
        float Hg[8];
#pragma unroll
        for (int e = 0; e < 8; ++e) Hg[e] = acc[e] + bvec[e];

        int a1 = 0;
#pragma unroll
        for (int e = 1; e < 8; ++e) if (Hg[e] > Hg[a1]) a1 = e;
        float m1 = Hg[a1];
        float m2 = -1e30f;
#pragma unroll
        for (int e = 0; e < 8; ++e) if (e != a1 && Hg[e] > m2) m2 = Hg[e];

        float ex[8]; float sum = 0.f;
#pragma unroll
        for (int e = 0; e < 8; ++e) { ex[e] = expf(Hg[e] - m1); sum += ex[e]; }
        float inv = 1.f / sum;
#pragma unroll
        for (int e = 0; e < 8; ++e)
            probs_out[(size_t)t * 8 + e] = ex[e] * inv;

        float den = 0.f;
#pragma unroll
        for (int e = 0; e < 8; ++e) if (Hg[e] >= m2) den += ex[e];
        float invd = 1.f / den;
        int n = 0;
#pragma unroll
        for (int e = 0; e < 8; ++e) {
            if (Hg[e] >= m2) {
                sel_e[t * 8 + n] = e;
                sel_g[t * 8 + n] = ex[e] * invd;
                ++n;
                atomicAdd(&counts[e], 1);
            }
        }
        sel_cnt[t] = n;
    }
}

// ---------------------------------------------------------------------------
// Kernel 2: scatter (with inline exclusive scan of the 8 expert counts).
// Each block computes the scan locally; block 0 publishes offsets[].
// ---------------------------------------------------------------------------
__global__ __launch_bounds__(256) void scatter_kernel(
    const int* __restrict__ sel_cnt,
    const int* __restrict__ sel_e,
    const float* __restrict__ sel_g,
    const int* __restrict__ counts,
    int* __restrict__ offsets,
    int* __restrict__ cursors,
    int* __restrict__ pair_token,
    float* __restrict__ pair_gate,
    int* __restrict__ tok_slot)
{
    __shared__ int offs_s[8];
    if (threadIdx.x == 0) {
        int tot = 0;
#pragma unroll
        for (int e = 0; e < 8; ++e) { offs_s[e] = tot; tot += counts[e]; }
        if (blockIdx.x == 0) {
#pragma unroll
            for (int e = 0; e < 8; ++e) offsets[e] = offs_s[e];
        }
    }
    __syncthreads();

    int t = blockIdx.x * blockDim.x + threadIdx.x;
    if (t >= NTOK) return;
    int n = sel_cnt[t];
    for (int i = 0; i < n && i < 8; ++i) {
        int e = sel_e[t * 8 + i];
        int r = atomicAdd(&cursors[e], 1);
        int slot = offs_s[e] + r;
        if (slot < CAP) {
            pair_token[slot] = t;
            pair_gate[slot]  = sel_g[t * 8 + i];
            tok_slot[t * 8 + i] = slot;
        } else {
            tok_slot[t * 8 + i] = -1;
        }
    }
}

// ---------------------------------------------------------------------------
// Kernel 4: fc1 grouped GEMM — R5-PROVEN 128x128 single-buffer structure.
// 1D grid, expert = wgid&7 (XCD pin), ntile fastest.
// h[slot] = relu(x_bf[tok] @ fc1_wb[e]^T + fc1_b[e])  (bf16 out)
// ---------------------------------------------------------------------------
__global__ __launch_bounds__(256) void fc1_kernel(
    const unsigned short* __restrict__ xs_bf,
    const unsigned short* __restrict__ fc1_wb,
    const float* __restrict__ fc1_b,
    const int* __restrict__ counts,
    const int* __restrict__ offsets,
    const int* __restrict__ pair_token,
    unsigned short* __restrict__ h)
{
    const int wg = blockIdx.x;
    const int e = wg & 7;               // XCD pin
    const int idx = wg >> 3;
    const int mtile = idx >> 4;         // ntile fastest
    const int ntile = idx & 15;
    const int cnt = counts[e];
    if (mtile * 128 >= cnt) return;
    const int offs = offsets[e];

    __shared__ __align__(16) unsigned short As[128 * 64];
    __shared__ __align__(16) unsigned short Bs[128 * 64];

    const int tid  = threadIdx.x;
    const int lane = tid & 63;
    const int wave = tid >> 6;
    const int wr = wave >> 1, wc = wave & 1;
    const int lrow = lane & 15;
    const int kq   = lane >> 4;

    const unsigned short* aSrc[4];
    const unsigned short* bSrc[4];
    int dstOff[4];
#pragma unroll
    for (int i = 0; i < 4; ++i) {
        int c = i * 256 + tid;          // 0..1023
        int row = c >> 3;
        int gran = (c & 7) ^ (row & 7); // G21 pre-swizzled source
        int m = mtile * 128 + row;
        int mc = m < cnt ? m : cnt - 1;
        int tok = pair_token[offs + mc];
        aSrc[i] = xs_bf + (size_t)tok * D_DIM + gran * 8;
        int n = ntile * 128 + row;
        bSrc[i] = fc1_wb + ((size_t)e * H_DIM + n) * D_DIM + gran * 8;
        dstOff[i] = (i * 256 + wave * 64) * 8;   // wave-uniform, linear
    }

    f32x4 acc[4][4];
#pragma unroll
    for (int i = 0; i < 4; ++i)
#pragma unroll
        for (int j = 0; j < 4; ++j)
            acc[i][j] = (f32x4){0.f, 0.f, 0.f, 0.f};

    for (int k0 = 0; k0 < D_DIM; k0 += 64) {
        __syncthreads();
#pragma unroll
        for (int i = 0; i < 4; ++i) {
            glds16(aSrc[i] + k0, &As[dstOff[i]]);
            glds16(bSrc[i] + k0, &Bs[dstOff[i]]);
        }
        __syncthreads();
#pragma unroll
        for (int ks = 0; ks < 2; ++ks) {
            bf16x8 af[4], bfr[4];
            const int gr = ks * 4 + kq;
            const int sg = (gr ^ (lrow & 7)) * 8;
#pragma unroll
            for (int i = 0; i < 4; ++i) {
                af[i]  = *(const bf16x8*)&As[(wr * 64 + i * 16 + lrow) * 64 + sg];
                bfr[i] = *(const bf16x8*)&Bs[(wc * 64 + i * 16 + lrow) * 64 + sg];
            }
#pragma unroll
            for (int i = 0; i < 4; ++i)
#pragma unroll
                for (int j = 0; j < 4; ++j)
                    acc[i][j] = __builtin_amdgcn_mfma_f32_16x16x32_bf16(af[i], bfr[j], acc[i][j], 0, 0, 0);
        }
    }

    int ncol[4]; float bias[4];
#pragma unroll
    for (int j = 0; j < 4; ++j) {
        ncol[j] = ntile * 128 + wc * 64 + j * 16 + lrow;
        bias[j] = fc1_b[e * H_DIM + ncol[j]];
    }
#pragma unroll
    for (int i = 0; i < 4; ++i) {
#pragma unroll
        for (int r = 0; r < 4; ++r) {
            int m = mtile * 128 + wr * 64 + i * 16 + kq * 4 + r;
            if (m < cnt) {
                size_t base = (size_t)(offs + m) * H_DIM;
#pragma unroll
                for (int j = 0; j < 4; ++j) {
                    float v = acc[i][j][r] + bias[j];
                    h[base + ncol[j]] = f2bf(v > 0.f ? v : 0.f);
                }
            }
        }
    }
}

// ---------------------------------------------------------------------------
// Kernel 5: fc2 — R8-measured-best 128x256 structure (unchanged).
// Plain bf16 stores of pre-gated eo_bf[slot] = (acc+bias)*g/S.
// ---------------------------------------------------------------------------
__global__ __launch_bounds__(256, 2) void fc2_kernel(
    const unsigned short* __restrict__ h,
    const unsigned short* __restrict__ fc2_wb,
    const float* __restrict__ fc2_b,
    const int* __restrict__ counts,
    const int* __restrict__ offsets,
    const float* __restrict__ pair_gate,
    unsigned short* __restrict__ eo_bf)
{
    const int wg = blockIdx.x;
    const int e = wg & 7;               // XCD pin
    const int idx = wg >> 3;
    const int mtile = idx >> 3;
    const int ntile = idx & 7;
    const int cnt = counts[e];
    if (mtile * 128 >= cnt) return;
    const int offs = offsets[e];

    __shared__ __align__(16) unsigned short As[128 * 64];
    __shared__ __align__(16) unsigned short Bs[256 * 64];

    const int tid  = threadIdx.x;
    const int lane = tid & 63;
    const int wid  = tid >> 6;
    const int lrow = lane & 15;
    const int kq   = lane >> 4;
    const int swz  = lrow & 7;

    const unsigned short* aSrc[4];
    int aDst[4];
#pragma unroll
    for (int i = 0; i < 4; ++i) {
        int c = i * 256 + tid;
        int row = c >> 3;
        int gran = (c & 7) ^ (row & 7);
        int m = mtile * 128 + row;
        int mc = m < cnt ? m : cnt - 1;
        aSrc[i] = h + (size_t)(offs + mc) * H_DIM + gran * 8;
        aDst[i] = (i * 256 + wid * 64) * 8;
    }
    const unsigned short* bSrc[8];
    int bDst[8];
#pragma unroll
    for (int i = 0; i < 8; ++i) {
        int c = i * 256 + tid;
        int row = c >> 3;
        int gran = (c & 7) ^ (row & 7);
        int n = ntile * 256 + row;
        bSrc[i] = fc2_wb + ((size_t)e * H_DIM + n) * H_DIM + gran * 8;
        bDst[i] = (i * 256 + wid * 64) * 8;
    }

    f32x4 acc[8][4];
#pragma unroll
    for (int i = 0; i < 8; ++i)
#pragma unroll
        for (int j = 0; j < 4; ++j)
            acc[i][j] = (f32x4){0.f, 0.f, 0.f, 0.f};

    for (int k0 = 0; k0 < H_DIM; k0 += 64) {
        __syncthreads();
#pragma unroll
        for (int i = 0; i < 4; ++i) glds16(aSrc[i] + k0, &As[aDst[i]]);
#pragma unroll
        for (int i = 0; i < 8; ++i) glds16(bSrc[i] + k0, &Bs[bDst[i]]);
        __syncthreads();
#pragma unroll
        for (int ks = 0; ks < 2; ++ks) {
            const int sg = ((ks * 4 + kq) ^ swz) * 8;
            bf16x8 af[8], bfr[4];
#pragma unroll
            for (int i = 0; i < 8; ++i)
                af[i] = *(const bf16x8*)&As[(i * 16 + lrow) * 64 + sg];
#pragma unroll
            for (int j = 0; j < 4; ++j)
                bfr[j] = *(const bf16x8*)&Bs[(wid * 64 + j * 16 + lrow) * 64 + sg];
#pragma unroll
            for (int i = 0; i < 8; ++i)
#pragma unroll
                for (int j = 0; j < 4; ++j)
                    acc[i][j] = __builtin_amdgcn_mfma_f32_16x16x32_bf16(
                        af[i], bfr[j], acc[i][j], 0, 0, 0);
        }
    }

    int ncol[4]; float bias[4];
#pragma unroll
    for (int j = 0; j < 4; ++j) {
        ncol[j] = ntile * 256 + wid * 64 + j * 16 + lrow;
        bias[j] = fc2_b[e * H_DIM + ncol[j]];
    }
#pragma unroll
    for (int i = 0; i < 8; ++i) {
#pragma unroll
        for (int r = 0; r < 4; ++r) {
            int m = mtile * 128 + i * 16 + kq * 4 + r;
            if (m < cnt) {
                int slot = offs + m;
                float g  = pair_gate[slot] * 0.5f;   // 1/S
                size_t base = (size_t)slot * H_DIM;
#pragma unroll
                for (int j = 0; j < 4; ++j) {
                    float v = (acc[i][j][r] + bias[j]) * g;
                    eo_bf[base + ncol[j]] = f2bf(v);
                }
            }
        }
    }
}

// ---------------------------------------------------------------------------
// Kernel 5b: gather-reduce. combined_bf[b][h] = sum over s,i of eo_bf[slot][h]
// ---------------------------------------------------------------------------
__global__ __launch_bounds__(256) void reduce_kernel(
    const int* __restrict__ sel_cnt,
    const int* __restrict__ tok_slot,
    const unsigned short* __restrict__ eo_bf,
    unsigned short* __restrict__ combined_bf)
{
    const int b = blockIdx.x;
    const int h0 = threadIdx.x * 8;

    float acc[8];
#pragma unroll
    for (int j = 0; j < 8; ++j) acc[j] = 0.f;

#pragma unroll
    for (int s = 0; s < S_DIM; ++s) {
        int t = s * B_DIM + b;
        int n = sel_cnt[t];
        for (int i = 0; i < n && i < 8; ++i) {
            int slot = tok_slot[t * 8 + i];
            if (slot < 0) continue;
            bf16x8 v = *(const bf16x8*)&eo_bf[(size_t)slot * H_DIM + h0];
#pragma unroll
            for (int j = 0; j < 8; ++j)
                acc[j] += bf2f((unsigned short)v[j]);
        }
    }

    int4 o;
    o.x = (int)pack2(acc[0], acc[1]);
    o.y = (int)pack2(acc[2], acc[3]);
    o.z = (int)pack2(acc[4], acc[5]);
    o.w = (int)pack2(acc[6], acc[7]);
    *(int4*)&combined_bf[(size_t)b * H_DIM + h0] = o;
}

// ---------------------------------------------------------------------------
// Kernel 6: final GEMM, all-bf16, single-buffer 128x128 (proven, unchanged).
// out = combined_bf @ final_wb^T + final_b (fp32 out)
// ---------------------------------------------------------------------------
__global__ __launch_bounds__(256) void final_kernel(
    const unsigned short* __restrict__ combined_bf,
    const unsigned short* __restrict__ final_wb,
    const float* __restrict__ final_b,
    float* __restrict__ out)
{
    const int mtile = blockIdx.y;
    const int ntile = blockIdx.x;

    __shared__ __align__(16) unsigned short As[128 * 64];
    __shared__ __align__(16) unsigned short Bs[128 * 64];

    const int tid  = threadIdx.x;
    const int lane = tid & 63;
    const int wave = tid >> 6;
    const int wr = wave >> 1, wc = wave & 1;
    const int lrow = lane & 15;
    const int kq   = lane >> 4;

    const unsigned short* aSrc[4];
    const unsigned short* bSrc[4];
    int dstOff[4];
#pragma unroll
    for (int i = 0; i < 4; ++i) {
        int c = i * 256 + tid;
        int row = c >> 3;
        int gran = (c & 7) ^ (row & 7);
        int m = mtile * 128 + row;
        aSrc[i] = combined_bf + (size_t)m * H_DIM + gran * 8;
        int n = ntile * 128 + row;
        bSrc[i] = final_wb + (size_t)n * H_DIM + gran * 8;
        dstOff[i] = (i * 256 + wave * 64) * 8;
    }

    f32x4 acc[4][4];
#pragma unroll
    for (int i = 0; i < 4; ++i)
#pragma unroll
        for (int j = 0; j < 4; ++j)
            acc[i][j] = (f32x4){0.f, 0.f, 0.f, 0.f};

    for (int k0 = 0; k0 < H_DIM; k0 += 64) {
        __syncthreads();
#pragma unroll
        for (int i = 0; i < 4; ++i) {
            glds16(aSrc[i] + k0, &As[dstOff[i]]);
            glds16(bSrc[i] + k0, &Bs[dstOff[i]]);
        }
        __syncthreads();
#pragma unroll
        for (int ks = 0; ks < 2; ++ks) {
            bf16x8 af[4], bfr[4];
            const int gr = ks * 4 + kq;
            const int sg = (gr ^ (lrow & 7)) * 8;
#pragma unroll
            for (int i = 0; i < 4; ++i) {
                af[i]  = *(const bf16x8*)&As[(wr * 64 + i * 16 + lrow) * 64 + sg];
                bfr[i] = *(const bf16x8*)&Bs[(wc * 64 + i * 16 + lrow) * 64 + sg];
            }
#pragma unroll
            for (int i = 0; i < 4; ++i)
#pragma unroll
                for (int j = 0; j < 4; ++j)
                    acc[i][j] = __builtin_amdgcn_mfma_f32_16x16x32_bf16(af[i], bfr[j], acc[i][j], 0, 0, 0);
        }
    }

    int ncol[4]; float bias[4];
#pragma unroll
    for (int j = 0; j < 4; ++j) {
        ncol[j] = ntile * 128 + wc * 64 + j * 16 + lrow;
        bias[j] = final_b[ncol[j]];
    }
#pragma unroll
    for (int i = 0; i < 4; ++i) {
#pragma unroll
        for (int r = 0; r < 4; ++r) {
            int m = mtile * 128 + wr * 64 + i * 16 + kq * 4 + r;
#pragma unroll
            for (int j = 0; j < 4; ++j)
                out[(size_t)m * O_DIM + ncol[j]] = acc[i][j][r] + bias[j];
        }
    }
}

// ---------------------------------------------------------------------------
extern "C" void kernel_launch(void* const* d_in, const int* in_sizes, int n_in,
                              void* d_out, int out_size, void* d_ws, size_t ws_size,
                              hipStream_t stream) {
    const float* xs      = (const float*)d_in[0];
    const float* Wg      = (const float*)d_in[1];
    const float* bvec    = (const float*)d_in[2];
    const float* fc1_w   = (const float*)d_in[3];
    const float* fc1_b   = (const float*)d_in[4];
    const float* fc2_w   = (const float*)d_in[5];
    const float* fc2_b   = (const float*)d_in[6];
    const float* final_w = (const float*)d_in[7];
    const float* final_b = (const float*)d_in[8];

    float* out = (float*)d_out;
    float* probs_out = out + (size_t)B_DIM * O_DIM;

    uint8_t* w = (uint8_t*)d_ws;
    int*   counts     = (int*)(w + 0);
    int*   cursors    = (int*)(w + 64);
    int*   offsets    = (int*)(w + 128);
    int*   sel_cnt    = (int*)(w + 256);        // 16 KB
    int*   sel_e      = (int*)(w + 0x5000);     // 128 KB
    float* sel_g      = (float*)(w + 0x25000);  // 128 KB
    int*   pair_token = (int*)(w + 0x45000);    // 48 KB
    float* pair_gate  = (float*)(w + 0x51000);  // 48 KB
    int*   tok_slot   = (int*)(w + 0x5D000);    // 128 KB -> 0x7D000
    unsigned short* h = (unsigned short*)(w + 0x1060000);       // 48 MB -> 0x4060000
    unsigned short* xs_bf   = (unsigned short*)(w + 0x4060000); // 8 MB  -> 0x4860000
    unsigned short* fc1_wb  = (unsigned short*)(w + 0x4860000); // 32 MB -> 0x6860000
    unsigned short* fc2_wb  = (unsigned short*)(w + 0x6860000); // 64 MB -> 0xA860000
    unsigned short* final_wb    = (unsigned short*)(w + 0xA860000); // 4 MB -> 0xAC60000
    unsigned short* combined_bf = (unsigned short*)(w + 0xAC60000); // 8 MB -> 0xB460000
    unsigned short* eo_bf       = (unsigned short*)(w + 0xB460000); // 48 MB -> 0xE460000

    // 1) fused weight convert (also zeroes counts/cursors/offsets region)
    convert_all_kernel<<<(int)(N8_TOTAL / 256), 256, 0, stream>>>(
        fc1_w, fc2_w, final_w, fc1_wb, fc2_wb, final_wb, (int*)w);

    // 2) gating (+ xs -> bf16)
    gating_kernel<<<NTOK / 4, 256, 0, stream>>>(xs, Wg, bvec, probs_out,
                                                counts, sel_cnt, sel_e, sel_g, xs_bf);

    // 3) scatter (inline scan; block 0 publishes offsets[])
    scatter_kernel<<<NTOK / 256, 256, 0, stream>>>(sel_cnt, sel_e, sel_g,
                                                   counts, offsets, cursors,
                                                   pair_token, pair_gate, tok_slot);

    // 4) fc1: R5-proven 128x128; expert = wgid&7 (XCD pin), ntile fastest.
    fc1_kernel<<<E_DIM * (NTOK / 128) * (H_DIM / 128), 256, 0, stream>>>(
        xs_bf, fc1_wb, fc1_b, counts, offsets, pair_token, h);

    // 5) fc2: R8 measured-best 128x256.
    fc2_kernel<<<E_DIM * (NTOK / 128) * (H_DIM / 256), 256, 0, stream>>>(
        h, fc2_wb, fc2_b, counts, offsets, pair_gate, eo_bf);

    // 6) gather-reduce
    reduce_kernel<<<B_DIM, 256, 0, stream>>>(sel_cnt, tok_slot, eo_bf, combined_bf);

    // 7) final GEMM
    final_kernel<<<dim3(O_DIM / 128, B_DIM / 128), 256, 0, stream>>>(
        combined_bf, final_wb, final_b, out);
}